// Round 4
// baseline (574.175 us; speedup 1.0000x reference)
//
#include <hip/hip_runtime.h>

// MoE fused kernel, MI355X gfx950 — Round 4: occupancy 2x (Mtile=32, 512thr,
// 4 waves/SIMD), spill-free register budget, coalesced conv kernels.
// Shapes: B=65536, D=512, C=101, E=8, H=256.
// out[b,c] = sum_{e,h} g[b,e]*relu(x@W1+b1)[b,e,h]*W2[e,h,c] + sum_e g[b,e]*b2[e,c]
// g = softmax(x@Wg+bg), gate logits folded into layer1 GEMM as cols 2048..2055.
//
// R4 law (from R2/R3 spills): barrier-free K-split => each wave holds a full
// output copy: acc2 = Mtile*128/64 regs. Mtile=32 -> 64 regs, so
// acc2(64)+acc1(16)+temps fits the 128-reg cap of launch_bounds(512,4)
// => 2 blocks/CU = 16 waves/CU (R3 was stuck at 8 with spills).
//
// MFMA layouts (m89/m120-verified):
//   A: A[m][k], m=lane&15, k=(lane>>4)*8+j (j=0..7)
//   B: B[k][n], n=lane&15, k=(lane>>4)*8+j
//   C/D: col=lane&15, row=(lane>>4)*4+reg

typedef __attribute__((ext_vector_type(8))) short short8x;
typedef __attribute__((ext_vector_type(4))) float float4x;

#define C_DIM 101

__device__ __forceinline__ unsigned short f2bf(float f) {
  unsigned int u = __builtin_bit_cast(unsigned int, f);
  u += 0x7fffu + ((u >> 16) & 1u);     // round-to-nearest-even
  return (unsigned short)(u >> 16);
}

// ---- W1 -> bf16 B-frag packed, coalesced via LDS tile.
// Block (e, kf): stage W1[e][kf*32..+32][0..256] (32x256), emit 16 ntile frags.
// W1bf slot: ((ntile*16+kf)*64 + lane)*8 + j ; ntile = e*16 + (h>>4).
__global__ __launch_bounds__(256) void conv_w1(const float* __restrict__ W1,
                                               unsigned short* __restrict__ out) {
  __shared__ unsigned short T[32 * 256];   // [d][h], 16 KB
  int e = blockIdx.x >> 4;
  int kf = blockIdx.x & 15;
  const float* src = W1 + ((size_t)e * 512 + kf * 32) * 256;
#pragma unroll
  for (int it = 0; it < 8; ++it) {
    int idx = threadIdx.x + it * 256;           // float4 index in 32x256
    float4 f = ((const float4*)src)[idx];
    unsigned long long p =
        (unsigned long long)f2bf(f.x) | ((unsigned long long)f2bf(f.y) << 16) |
        ((unsigned long long)f2bf(f.z) << 32) | ((unsigned long long)f2bf(f.w) << 48);
    *(unsigned long long*)&T[idx * 4] = p;
  }
  __syncthreads();
  int l = threadIdx.x & 63;
  int wv = threadIdx.x >> 6;
#pragma unroll
  for (int i = 0; i < 4; ++i) {
    int ntl = wv * 4 + i;                       // local ntile 0..15
    int h = ntl * 16 + (l & 15);
    int dloc = (l >> 4) * 8;
    short8x v;
#pragma unroll
    for (int j = 0; j < 8; ++j) v[j] = (short)T[(dloc + j) * 256 + h];
    int ntile = e * 16 + ntl;
    *(short8x*)(out + ((size_t)(ntile * 16 + kf) * 64 + l) * 8) = v;
  }
}

// ---- Wg -> gate frags (ntile 128), cols 8..15 zero. 16 kf x 64 lanes.
__global__ __launch_bounds__(256) void conv_wg(const float* __restrict__ Wg,
                                               unsigned short* __restrict__ out) {
  int s = blockIdx.x * 256 + threadIdx.x;       // 0..1023
  int l = s & 63;
  int kf = s >> 6;
  int col = l & 15;
  int k = kf * 32 + (l >> 4) * 8;
  short8x v;
#pragma unroll
  for (int j = 0; j < 8; ++j)
    v[j] = (col < 8) ? (short)f2bf(Wg[(size_t)(k + j) * 8 + col]) : (short)0;
  *(short8x*)(out + ((size_t)(128 * 16 + kf) * 64 + l) * 8) = v;
}

// ---- W2 -> bf16 B-frag packed, coalesced via LDS. Block = expert e.
// W2bf slot: ((ct*64 + e*8 + kfl)*64 + lane)*8 + j
__global__ __launch_bounds__(256) void conv_w2(const float* __restrict__ W2,
                                               unsigned short* __restrict__ out) {
  __shared__ unsigned short T[256 * 104];  // [h][c pad 104], 53 KB
  int e = blockIdx.x;
  const float* src = W2 + (size_t)e * 256 * C_DIM;
  for (int it = 0; it < 101; ++it) {
    int idx = it * 256 + threadIdx.x;           // 0..25855
    float f = src[idx];
    int h = idx / C_DIM;
    int c = idx - h * C_DIM;
    T[h * 104 + c] = f2bf(f);
  }
  __syncthreads();
  int l = threadIdx.x & 63;
  int wv = threadIdx.x >> 6;
  int c = l & 15;
#pragma unroll
  for (int i = 0; i < 16; ++i) {
    int fid = wv * 16 + i;                      // 0..63 = ct*8 + kfl
    int ct = fid >> 3;
    int kfl = fid & 7;
    int cc = ct * 16 + c;
    int h = kfl * 32 + (l >> 4) * 8;
    short8x v;
#pragma unroll
    for (int j = 0; j < 8; ++j)
      v[j] = (cc < C_DIM) ? (short)T[(h + j) * 104 + cc] : (short)0;
    *(short8x*)(out + ((size_t)(ct * 64 + e * 8 + kfl) * 64 + l) * 8) = v;
  }
}

// ---- fused main kernel: 32 rows/block, 512 threads (8 waves), 2 blocks/CU
__global__ __launch_bounds__(512, 4) void moe_main(
    const float* __restrict__ x, const float* __restrict__ b1,
    const float* __restrict__ b2, const float* __restrict__ bg,
    const unsigned short* __restrict__ W1bf, const unsigned short* __restrict__ W2bf,
    float* __restrict__ out) {
  __shared__ float4x pool4[3136];                         // 50176 B
  unsigned short* xA = (unsigned short*)pool4;            // [0,32K): x A-frags [mt*16+kf][64][8]
  unsigned short* hA = xA + 16384;                        // [32K,48K): 8 x 2KB wave-private h'
  float* graw = (float*)hA;                               // alias (pre-loop only) [32][8]
  float* gt   = (float*)((char*)pool4 + 49152);           // [48K,49K): gates^T [8][32]
  float* red  = (float*)pool4;                            // post-loop alias [0,28K)

  const int tid = threadIdx.x;
  const int w = tid >> 6;     // wave 0..7
  const int l = tid & 63;     // lane
  const int quad = l >> 4;
  const int r0 = blockIdx.x * 32;
  unsigned short* hAw = hA + w * 1024;                    // wave-private 2 KB

  // ---- stage x -> bf16 A-frag LDS (coalesced float4 x2, b128 LDS writes)
#pragma unroll
  for (int it = 0; it < 4; ++it) {
    int g = tid + it * 512;            // m = g>>6 (0..31), k0 = (g&63)*8
    int m = g >> 6;
    int k0 = (g & 63) << 3;
    const float* src = x + (size_t)(r0 + m) * 512 + k0;
    float4 f0 = *(const float4*)src;
    float4 f1 = *(const float4*)(src + 4);
    short8x v;
    v[0] = (short)f2bf(f0.x); v[1] = (short)f2bf(f0.y);
    v[2] = (short)f2bf(f0.z); v[3] = (short)f2bf(f0.w);
    v[4] = (short)f2bf(f1.x); v[5] = (short)f2bf(f1.y);
    v[6] = (short)f2bf(f1.z); v[7] = (short)f2bf(f1.w);
    int mt = m >> 4;
    int kfrag = k0 >> 5;
    int lane = (((k0 >> 3) & 3) << 4) | (m & 15);
    *(short8x*)&xA[(size_t)(((mt << 4) | kfrag) * 64 + lane) * 8] = v;
  }
  __syncthreads();

  // ---- gate logits: waves 0,1 -> 16-row tiles vs gate frags (ntile 128)
  if (w < 2) {
    float4x acc = {0.f, 0.f, 0.f, 0.f};
    for (int kf = 0; kf < 16; ++kf) {
      short8x a = *(const short8x*)&xA[(size_t)((w * 16 + kf) * 64 + l) * 8];
      short8x b = *(const short8x*)(W1bf + ((size_t)(128 * 16 + kf) * 512 + l * 8));
      acc = __builtin_amdgcn_mfma_f32_16x16x32_bf16(a, b, acc, 0, 0, 0);
    }
    int col = l & 15;
    if (col < 8) {
      float bgv = bg[col];
#pragma unroll
      for (int r = 0; r < 4; ++r) {
        int row = (quad << 2) + r;
        graw[(w * 16 + row) * 8 + col] = acc[r] + bgv;
      }
    }
  }
  __syncthreads();
  // softmax over E=8 per row; write transposed gt[e][row]
  if (tid < 32) {
    float v[8], mx = -1e30f;
#pragma unroll
    for (int e = 0; e < 8; ++e) { v[e] = graw[tid * 8 + e]; mx = fmaxf(mx, v[e]); }
    float s = 0.f;
#pragma unroll
    for (int e = 0; e < 8; ++e) { v[e] = expf(v[e] - mx); s += v[e]; }
    float inv = 1.f / s;
#pragma unroll
    for (int e = 0; e < 8; ++e) gt[e * 32 + tid] = v[e] * inv;
  }
  __syncthreads();

  // ---- main loop over 8 N-tiles (expert e == nt), NO barriers
  float4x zero = {0.f, 0.f, 0.f, 0.f};
  float4x acc2[2][8];
#pragma unroll
  for (int mt = 0; mt < 2; ++mt)
#pragma unroll
    for (int ct = 0; ct < 8; ++ct) acc2[mt][ct] = zero;

  for (int nt = 0; nt < 8; ++nt) {
    // layer1: wave w -> h-cols [nt*256 + w*32, +32), all 32 rows
    float4x acc1[2][2];
    acc1[0][0] = zero; acc1[0][1] = zero; acc1[1][0] = zero; acc1[1][1] = zero;
#pragma unroll 2
    for (int kf = 0; kf < 16; ++kf) {
      short8x a0 = *(const short8x*)&xA[(size_t)((0 * 16 + kf) * 64 + l) * 8];
      short8x a1 = *(const short8x*)&xA[(size_t)((1 * 16 + kf) * 64 + l) * 8];
#pragma unroll
      for (int nc = 0; nc < 2; ++nc) {
        int ntile = nt * 16 + w * 2 + nc;
        short8x b = *(const short8x*)(W1bf + ((size_t)(ntile * 16 + kf) * 512 + l * 8));
        acc1[0][nc] = __builtin_amdgcn_mfma_f32_16x16x32_bf16(a0, b, acc1[0][nc], 0, 0, 0);
        acc1[1][nc] = __builtin_amdgcn_mfma_f32_16x16x32_bf16(a1, b, acc1[1][nc], 0, 0, 0);
      }
    }

    // epilogue: +b1, relu, *gate(e==nt), bf16 -> wave-private hA (C->A transpose)
#pragma unroll
    for (int nc = 0; nc < 2; ++nc) {
      int cin = nc * 16 + (l & 15);
      int n = nt * 256 + w * 32 + cin;
      float b1v = b1[n];
      int jj = cin & 7;
      int chunk = cin >> 3;
#pragma unroll
      for (int mt = 0; mt < 2; ++mt) {
        float4x gv = *(const float4x*)&gt[nt * 32 + mt * 16 + quad * 4];
#pragma unroll
        for (int r = 0; r < 4; ++r) {
          float hv = fmaxf(acc1[mt][nc][r] + b1v, 0.f) * gv[r];
          hAw[mt * 512 + (chunk * 16 + quad * 4 + r) * 8 + jj] = f2bf(hv);
        }
      }
    }

    // layer2 partial: K-slice = this wave's 32 h-cols (kf2 = nt*8+w), all 8 ct
    int kf2 = nt * 8 + w;
    short8x a20 = *(const short8x*)&hAw[0 * 512 + l * 8];
    short8x a21 = *(const short8x*)&hAw[1 * 512 + l * 8];
#pragma unroll
    for (int ct = 0; ct < 8; ++ct) {
      short8x b = *(const short8x*)(W2bf + ((size_t)(ct * 64 + kf2) * 512 + l * 8));
      acc2[0][ct] = __builtin_amdgcn_mfma_f32_16x16x32_bf16(a20, b, acc2[0][ct], 0, 0, 0);
      acc2[1][ct] = __builtin_amdgcn_mfma_f32_16x16x32_bf16(a21, b, acc2[1][ct], 0, 0, 0);
    }
  }

  // ---- cross-wave reduction: 4 sub-phases (mt x ct-half), 28 KB red region
  __syncthreads();
  int cl = l & 15;
#pragma unroll
  for (int mt = 0; mt < 2; ++mt) {
#pragma unroll
    for (int half = 0; half < 2; ++half) {
#pragma unroll
      for (int ci = 0; ci < 4; ++ci) {
        int ct = half * 4 + ci;
        if (ct != w) {
          int s = w - (w > ct ? 1 : 0);     // 0..6
          *(float4x*)&red[((ci * 7 + s) * 64 + l) * 4] = acc2[mt][ct];
        }
      }
      __syncthreads();
      if ((w >> 2) == half) {
        int ci = w & 3;
        float4x sum = acc2[mt][w];
#pragma unroll
        for (int s = 0; s < 7; ++s)
          sum += *(const float4x*)&red[((ci * 7 + s) * 64 + l) * 4];
        int c = w * 16 + cl;
        if (c < C_DIM) {
#pragma unroll
          for (int r = 0; r < 4; ++r) {
            int row = mt * 16 + quad * 4 + r;
            float bias = 0.f;
#pragma unroll
            for (int e = 0; e < 8; ++e) bias += gt[e * 32 + row] * b2[e * C_DIM + c];
            out[(size_t)(r0 + row) * C_DIM + c] = sum[r] + bias;
          }
        }
      }
      __syncthreads();
    }
  }
}

extern "C" void kernel_launch(void* const* d_in, const int* in_sizes, int n_in,
                              void* d_out, int out_size, void* d_ws, size_t ws_size,
                              hipStream_t stream) {
  const float* x  = (const float*)d_in[0];
  const float* W1 = (const float*)d_in[1];
  const float* b1 = (const float*)d_in[2];
  const float* W2 = (const float*)d_in[3];
  const float* b2 = (const float*)d_in[4];
  const float* Wg = (const float*)d_in[5];
  const float* bg = (const float*)d_in[6];
  float* out = (float*)d_out;

  unsigned short* W1bf = (unsigned short*)d_ws;                       // 129*16*512 u16
  unsigned short* W2bf = (unsigned short*)((char*)d_ws + (size_t)129 * 16 * 512 * 2);

  conv_w1<<<128, 256, 0, stream>>>(W1, W1bf);    // 8 e x 16 kf
  conv_wg<<<4, 256, 0, stream>>>(Wg, W1bf);      // gate ntile 128
  conv_w2<<<8, 256, 0, stream>>>(W2, W2bf);      // per expert
  moe_main<<<2048, 512, 0, stream>>>(x, b1, b2, bg, W1bf, W2bf, out);
}